// Round 1
// baseline (51.135 us; speedup 1.0000x reference)
//
#include <hip/hip_runtime.h>
#include <cstdint>
#include <cstddef>

typedef short short8 __attribute__((ext_vector_type(8)));
typedef float f32x4 __attribute__((ext_vector_type(4)));

#define BB 16
#define SS 512
#define TT 64
#define LL 64
#define UU 128

// ws layout (bytes) — hi-only W fragments
#define WT_OFF    0u                      // W_trans frags: 32 x 1KB = 32KB
#define WHT_OFF   (WT_OFF + 32768u)       // W_ht frags: 64 x 1KB = 64KB
#define WREL_OFF  (WHT_OFF + 65536u)      // W_rel frags: 32 x 1KB = 32KB
#define EMBBF_OFF (WREL_OFF + 32768u)     // emb bf16 table: 10.24MB
#define EMBBF_BYTES (40000u * 128u * 2u)

#if defined(__has_builtin)
#  if __has_builtin(__builtin_amdgcn_global_load_lds)
#    define USE_GLDS 1
#  endif
#endif
#ifndef USE_GLDS
#  define USE_GLDS 0
#endif

__device__ __forceinline__ unsigned short f2bf(float x) {  // rtne f32->bf16
  unsigned u = __float_as_uint(x);
  unsigned r = ((u >> 16) & 1u) + 0x7FFFu;
  return (unsigned short)((u + r) >> 16);
}
__device__ __forceinline__ float ftanh(float x) {  // 1 - 2/(e^2x+1)
  float e = __expf(2.0f * x);
  return 1.0f - __fdividef(2.0f, e + 1.0f);
}
// packed rtne pair convert: lo=cvt(a), hi=cvt(b)
__device__ __forceinline__ unsigned cvtpk(float a, float b) {
  unsigned r;
  asm("v_cvt_pk_bf16_f32 %0, %1, %2" : "=v"(r) : "v"(a), "v"(b));
  return r;
}
// 16-lane (DPP row) sum — pure VALU, replaces 4x ds_swizzle shuffle.
// xor1 = quad_perm[1,0,3,2] (0xB1), xor2 = quad_perm[2,3,0,1] (0x4E),
// then row_half_mirror (0x141: quads uniform -> acts as xor4),
// then row_mirror (0x140: 8-groups uniform -> acts as xor8).
__device__ __forceinline__ float row16_sum(float x) {
  x += __int_as_float(__builtin_amdgcn_update_dpp(0, __float_as_int(x), 0xB1, 0xF, 0xF, true));
  x += __int_as_float(__builtin_amdgcn_update_dpp(0, __float_as_int(x), 0x4E, 0xF, 0xF, true));
  x += __int_as_float(__builtin_amdgcn_update_dpp(0, __float_as_int(x), 0x141, 0xF, 0xF, true));
  x += __int_as_float(__builtin_amdgcn_update_dpp(0, __float_as_int(x), 0x140, 0xF, 0xF, true));
  return x;
}
#if USE_GLDS
// async 16B global->LDS DMA; LDS dest must be wave-uniform base + lane*16
// (our staging index o = wavebase + lane satisfies this exactly).
__device__ __forceinline__ void g2lds16(const void* g, void* l) {
  __builtin_amdgcn_global_load_lds(
      (const unsigned int __attribute__((address_space(1)))*)g,
      (unsigned int __attribute__((address_space(3)))*)l, 16, 0, 0);
}
#endif

// ---- prep: pack W into bf16 fragments (hi only) + convert emb table ----
// Frag (16x16x32, A/B symmetric): lane l holds W[kt*32+(l>>4)*8+j][nt*16+(l&15)].
// pairIdx=(kt*8+nt): [pairIdx*1024 + lane*16].
__global__ void prep_kernel(const float* __restrict__ Wt,
                            const float* __restrict__ Wht,
                            const float* __restrict__ Wrel,
                            const float* __restrict__ ef,
                            unsigned char* __restrict__ ws) {
  int blk = blockIdx.x;
  if (blk < 32) {
    int slot = blk * 256 + threadIdx.x;      // 8192 slots
    const float* W;
    unsigned char* base;
    if (slot < 2048)      { W = Wt;   base = ws + WT_OFF; }
    else if (slot < 6144) { W = Wht;  base = ws + WHT_OFF;  slot -= 2048; }
    else                  { W = Wrel; base = ws + WREL_OFF; slot -= 6144; }
    int lane = slot & 63, pair = slot >> 6;
    int n  = (pair & 7) * 16 + (lane & 15);
    int k0 = (pair >> 3) * 32 + (lane >> 4) * 8;
    short8 hv;
    #pragma unroll
    for (int j = 0; j < 8; ++j)
      hv[j] = (short)f2bf(W[(size_t)(k0 + j) * UU + n]);
    *reinterpret_cast<short8*>(base + (size_t)pair * 1024 + lane * 16) = hv;
  } else {
    // emb f32 -> bf16: 640000 short8-slots over 2500 blocks
    int i = (blk - 32) * 256 + threadIdx.x;
    const float4 a = reinterpret_cast<const float4*>(ef)[i * 2];
    const float4 b = reinterpret_cast<const float4*>(ef)[i * 2 + 1];
    short8 v;
    v[0] = (short)f2bf(a.x); v[1] = (short)f2bf(a.y);
    v[2] = (short)f2bf(a.z); v[3] = (short)f2bf(a.w);
    v[4] = (short)f2bf(b.x); v[5] = (short)f2bf(b.y);
    v[6] = (short)f2bf(b.z); v[7] = (short)f2bf(b.w);
    reinterpret_cast<short8*>(ws + EMBBF_OFF)[i] = v;
  }
}

// ---- fused per-(b,t) kernel: 1024 blocks x 1024 threads (16 waves) ---------
// Wave split (both GEMMs): ntp = w&3 owns n-tiles {2ntp, 2ntp+1}; grp = w>>2
// owns 3 row-tiles (GEMM1) / 1 m-tile (GEMM2). Every LDS fragment read feeds
// TWO MFMAs (2-nt reuse) — halves DS-pipe reads vs 1-nt layout; W streams
// from L2 instead (VMEM pipe is idle).  TEB swizzle: logical 16B-chunk c16 of
// row r at physical chunk c16^(r&15).  e_weight reduced with DPP (no LDS).
template<bool PRE>
__launch_bounds__(1024, 8)
__global__ void fused_bt(const int* __restrict__ triples,
                         const float* __restrict__ emb_f32,
                         const unsigned short* __restrict__ emb_bf,
                         const float* __restrict__ b_trans,
                         const float* __restrict__ b_ht,
                         const float* __restrict__ b_rel,
                         const int* __restrict__ sent_triples,
                         const unsigned char* __restrict__ wsr,
                         float* __restrict__ out) {
  __shared__ unsigned short TEB[192 * 128];    // 48KB: emb staging -> te
  __shared__ float EWt[4][64];                 // e_weight partials (per ntp)
  __shared__ float ALPHA[64];
  __shared__ float PART[8][256];               // wsum partials (8 l-groups)
  __shared__ int MATCH[512];                   // live from GEMM1 to scatter
  __shared__ int NM;

  const int tid  = threadIdx.x;
  const int bt   = blockIdx.x;
  const int w    = tid >> 6;      // wave id 0..15
  const int lane = tid & 63;
  const int li   = lane & 15;
  const int lg   = lane >> 4;
  const int ntp  = w & 3;
  const int nt0  = ntp * 2, nt1 = nt0 + 1;
  const int grp  = w >> 2;        // 0..3

  const unsigned char* wtb  = wsr + WT_OFF;
  const unsigned char* whtb = wsr + WHT_OFF;
  const unsigned char* wrlb = wsr + WREL_OFF;

  if (tid == 0) NM = 0;

  // ---- stage ALL 192 emb rows into TEB (3 slots/thread) ------------------
  // Source address carries the swizzle; LDS dest is linear (DMA-compatible).
  if (PRE) {
#if USE_GLDS
    #pragma unroll
    for (int j = 0; j < 3; ++j) {
      int o = tid + j * 1024;             // 3072 slots = 192 rows x 16 chunks
      int row = o >> 4, pc = o & 15;
      int tok = triples[(size_t)bt * 192 + row];
      g2lds16(emb_bf + (size_t)tok * UU + ((pc ^ (row & 15)) << 3),
              &TEB[o * 8]);
    }
#else
    short8 st[3];
    #pragma unroll
    for (int j = 0; j < 3; ++j) {
      int o = tid + j * 1024, row = o >> 4, pc = o & 15;
      int tok = triples[(size_t)bt * 192 + row];
      st[j] = *reinterpret_cast<const short8*>(
          emb_bf + (size_t)tok * UU + ((pc ^ (row & 15)) << 3));
    }
    #pragma unroll
    for (int j = 0; j < 3; ++j) {
      int o = tid + j * 1024;
      *reinterpret_cast<short8*>(&TEB[o * 8]) = st[j];
    }
#endif
  } else {
    short8 st[3];
    #pragma unroll
    for (int j = 0; j < 3; ++j) {
      int o = tid + j * 1024, row = o >> 4, pc = o & 15;
      int tok = triples[(size_t)bt * 192 + row];
      const float* fb = emb_f32 + (size_t)tok * UU + ((pc ^ (row & 15)) << 3);
      float4 x = *reinterpret_cast<const float4*>(fb);
      float4 y = *reinterpret_cast<const float4*>(fb + 4);
      st[j][0]=(short)f2bf(x.x); st[j][1]=(short)f2bf(x.y);
      st[j][2]=(short)f2bf(x.z); st[j][3]=(short)f2bf(x.w);
      st[j][4]=(short)f2bf(y.x); st[j][5]=(short)f2bf(y.y);
      st[j][6]=(short)f2bf(y.z); st[j][7]=(short)f2bf(y.w);
    }
    #pragma unroll
    for (int j = 0; j < 3; ++j) {
      int o = tid + j * 1024;
      *reinterpret_cast<short8*>(&TEB[o * 8]) = st[j];
    }
  }

  // GEMM1 kt=0 W pair — latency fully hidden behind the staging barrier
  short8 Wa = *reinterpret_cast<const short8*>(wtb + (size_t)nt0 * 1024 + lane * 16);
  short8 Wb = *reinterpret_cast<const short8*>(wtb + (size_t)nt1 * 1024 + lane * 16);
  __syncthreads();  // staging + NM ready

  // ---- match-find, hoisted to overlap GEMM1 (atomics done by next barrier)
  if (tid < SS) {
    int idx = sent_triples[(bt >> 6) * SS + tid];
    if (idx == (bt & 63)) MATCH[atomicAdd(&NM, 1)] = tid;
  }

  // ============ GEMM1: 3 row-tiles x 2 n-tiles, read phase ================
  f32x4 acc[3][2];
  #pragma unroll
  for (int q = 0; q < 3; ++q) {
    acc[q][0] = f32x4{0.f, 0.f, 0.f, 0.f};
    acc[q][1] = f32x4{0.f, 0.f, 0.f, 0.f};
  }
  #pragma unroll
  for (int kt = 0; kt < 4; ++kt) {
    if (kt > 0) {  // load-at-use keeps peak W regs at 16 (VGPR<=64 for 8 w/EU)
      Wa = *reinterpret_cast<const short8*>(
          wtb + (size_t)(kt * 8 + nt0) * 1024 + lane * 16);
      Wb = *reinterpret_cast<const short8*>(
          wtb + (size_t)(kt * 8 + nt1) * 1024 + lane * 16);
    }
    #pragma unroll
    for (int q = 0; q < 3; ++q) {
      const short8 bfr = *reinterpret_cast<const short8*>(
          &TEB[((grp * 3 + q) * 16 + li) * 128 + (((kt * 4 + lg) ^ li) << 3)]);
      acc[q][0] = __builtin_amdgcn_mfma_f32_16x16x32_bf16(Wa, bfr, acc[q][0], 0, 0, 0);
      acc[q][1] = __builtin_amdgcn_mfma_f32_16x16x32_bf16(Wb, bfr, acc[q][1], 0, 0, 0);
    }
  }
  __syncthreads();  // ALL emb reads complete before any te overwrite

  // ============ GEMM1 write phase: te in one pass =========================
  const float4 btrA = *reinterpret_cast<const float4*>(b_trans + nt0 * 16 + lg * 4);
  const float4 btrB = *reinterpret_cast<const float4*>(b_trans + nt1 * 16 + lg * 4);
  const int hb8  = (lg & 1) << 3;
  const int cc8A = nt0 * 2 + (lg >> 1);
  const int cc8B = cc8A + 2;
  #pragma unroll
  for (int q = 0; q < 3; ++q) {
    int row = (grp * 3 + q) * 16 + li;   // row & 15 == li
    char* base = reinterpret_cast<char*>(TEB) + row * 256;
    {
      float v0 = ftanh(acc[q][0][0] + btrA.x);
      float v1 = ftanh(acc[q][0][1] + btrA.y);
      float v2 = ftanh(acc[q][0][2] + btrA.z);
      float v3 = ftanh(acc[q][0][3] + btrA.w);
      uint2 pk = { cvtpk(v0, v1), cvtpk(v2, v3) };
      *reinterpret_cast<uint2*>(base + (((cc8A ^ li) << 4) | hb8)) = pk;
    }
    {
      float v0 = ftanh(acc[q][1][0] + btrB.x);
      float v1 = ftanh(acc[q][1][1] + btrB.y);
      float v2 = ftanh(acc[q][1][2] + btrB.z);
      float v3 = ftanh(acc[q][1][3] + btrB.w);
      uint2 pk = { cvtpk(v0, v1), cvtpk(v2, v3) };
      *reinterpret_cast<uint2*>(base + (((cc8B ^ li) << 4) | hb8)) = pk;
    }
  }

  // prefetch GEMM2 first W pair before the barrier
  short8 Wc0 = *reinterpret_cast<const short8*>(whtb + (size_t)nt0 * 1024 + lane * 16);
  short8 Wc1 = *reinterpret_cast<const short8*>(whtb + (size_t)nt1 * 1024 + lane * 16);
  __syncthreads();  // te complete

  // ============ GEMM2: 1 m-tile x 2 n-tiles (A-frag read feeds 2 MFMAs) ===
  // head = te row 3l+0, rel = 3l+1, tail = 3l+2  (l = m*16 + li)
  const int m    = grp;
  const int rowb = 48 * m + 3 * li;
  const float bh0 = b_ht[nt0 * 16 + li],  bh1 = b_ht[nt1 * 16 + li];
  const float br0 = b_rel[nt0 * 16 + li], br1 = b_rel[nt1 * 16 + li];
  f32x4 aH0{0.f,0.f,0.f,0.f}, aH1{0.f,0.f,0.f,0.f};
  f32x4 aR0{0.f,0.f,0.f,0.f}, aR1{0.f,0.f,0.f,0.f};

  #pragma unroll
  for (int kt = 0; kt < 8; ++kt) {   // head_tail: K=256
    short8 Wn0, Wn1;
    if (kt < 7) {
      Wn0 = *reinterpret_cast<const short8*>(
          whtb + (size_t)((kt + 1) * 8 + nt0) * 1024 + lane * 16);
      Wn1 = *reinterpret_cast<const short8*>(
          whtb + (size_t)((kt + 1) * 8 + nt1) * 1024 + lane * 16);
    } else {
      Wn0 = *reinterpret_cast<const short8*>(wrlb + (size_t)nt0 * 1024 + lane * 16);
      Wn1 = *reinterpret_cast<const short8*>(wrlb + (size_t)nt1 * 1024 + lane * 16);
    }
    const int row = rowb + ((kt < 4) ? 0 : 2);
    const int c16 = (kt & 3) * 4 + lg;
    const short8 a = *reinterpret_cast<const short8*>(
        &TEB[row * 128 + ((c16 ^ (row & 15)) << 3)]);
    aH0 = __builtin_amdgcn_mfma_f32_16x16x32_bf16(a, Wc0, aH0, 0, 0, 0);
    aH1 = __builtin_amdgcn_mfma_f32_16x16x32_bf16(a, Wc1, aH1, 0, 0, 0);
    Wc0 = Wn0; Wc1 = Wn1;
  }
  #pragma unroll
  for (int kt = 0; kt < 4; ++kt) {   // relation: K=128, rows 3l+1
    short8 Wn0, Wn1;
    if (kt < 3) {
      Wn0 = *reinterpret_cast<const short8*>(
          wrlb + (size_t)((kt + 1) * 8 + nt0) * 1024 + lane * 16);
      Wn1 = *reinterpret_cast<const short8*>(
          wrlb + (size_t)((kt + 1) * 8 + nt1) * 1024 + lane * 16);
    }
    const int row = rowb + 1;
    const int c16 = kt * 4 + lg;
    const short8 a = *reinterpret_cast<const short8*>(
        &TEB[row * 128 + ((c16 ^ (row & 15)) << 3)]);
    aR0 = __builtin_amdgcn_mfma_f32_16x16x32_bf16(a, Wc0, aR0, 0, 0, 0);
    aR1 = __builtin_amdgcn_mfma_f32_16x16x32_bf16(a, Wc1, aR1, 0, 0, 0);
    if (kt < 3) { Wc0 = Wn0; Wc1 = Wn1; }
  }

  // e_weight partials: l = m*16 + lg*4 + r; DPP-reduce over the 16 li lanes
  #pragma unroll
  for (int r = 0; r < 4; ++r) {
    float p = ftanh(aH0[r] + bh0) * (aR0[r] + br0)
            + ftanh(aH1[r] + bh1) * (aR1[r] + br1);
    p = row16_sum(p);
    if (li == 0) EWt[ntp][m * 16 + lg * 4 + r] = p;
  }
  __syncthreads();

  // ============ softmax over L=64 (wave 0) =================================
  if (tid < 64) {
    float e = EWt[0][tid] + EWt[1][tid] + EWt[2][tid] + EWt[3][tid];
    float mx = e;
    #pragma unroll
    for (int off = 32; off > 0; off >>= 1)
      mx = fmaxf(mx, __shfl_xor(mx, off, 64));
    float ex = __expf(e - mx);
    float sm = ex;
    #pragma unroll
    for (int off = 32; off > 0; off >>= 1)
      sm += __shfl_xor(sm, off, 64);
    ALPHA[tid] = ex / sm;
  }
  __syncthreads();

  // ============ weighted sum: paired-bf16 b32 reads, 8 l's per thread ======
  {
    int cp  = tid & 127, lgp = tid >> 7;   // col-pair, l-group (8 l's)
    int c0  = cp << 1;
    int k   = (c0 >> 7) << 1;              // head rows 3l, tail rows 3l+2
    int cc  = c0 & 127;
    int w8  = cc >> 3, bofs = (cc & 7) << 1;
    float4 a03 = *reinterpret_cast<const float4*>(&ALPHA[lgp * 8]);
    float4 a47 = *reinterpret_cast<const float4*>(&ALPHA[lgp * 8 + 4]);
    float o0 = 0.f, o1 = 0.f;
    #pragma unroll
    for (int j = 0; j < 8; ++j) {
      int l = lgp * 8 + j;
      int row = 3 * l + k;
      unsigned u = *reinterpret_cast<const unsigned*>(
          reinterpret_cast<const char*>(TEB) + row * 256 +
          (((w8 ^ (row & 15)) << 4) | bofs));
      float al = (j < 4) ? a03[j] : a47[j - 4];
      o0 = fmaf(al, __uint_as_float(u << 16), o0);
      o1 = fmaf(al, __uint_as_float(u & 0xFFFF0000u), o1);
    }
    *reinterpret_cast<float2*>(&PART[lgp][c0]) = make_float2(o0, o1);
  }
  __syncthreads();  // all ALPHA reads + PART writes complete

  if (tid < 256) {
    float s = 0.f;
    #pragma unroll
    for (int g = 0; g < 8; ++g) s += PART[g][tid];
    PART[0][tid] = s;
  }
  __syncthreads();

  // ============ cooperative scatter: wave-per-row coalesced copies =========
  {
    int b = bt >> 6;
    const int nm = NM;
    const float4 v = reinterpret_cast<const float4*>(&PART[0][0])[lane];
    for (int q = w; q < nm; q += 16) {
      int s = MATCH[q];
      reinterpret_cast<float4*>(out + ((size_t)(b * SS + s)) * 256)[lane] = v;
    }
  }
}

extern "C" void kernel_launch(void* const* d_in, const int* in_sizes, int n_in,
                              void* d_out, int out_size, void* d_ws, size_t ws_size,
                              hipStream_t stream) {
  const int*   triples      = (const int*)d_in[1];
  const int*   sent_triples = (const int*)d_in[2];
  const float* emb_table    = (const float*)d_in[3];
  const float* W_trans      = (const float*)d_in[4];
  const float* b_trans      = (const float*)d_in[5];
  const float* W_ht         = (const float*)d_in[6];
  const float* b_ht         = (const float*)d_in[7];
  const float* W_rel        = (const float*)d_in[8];
  const float* b_rel        = (const float*)d_in[9];
  float* out = (float*)d_out;
  unsigned char* ws = (unsigned char*)d_ws;
  unsigned short* emb_bf = (unsigned short*)(ws + EMBBF_OFF);

  const bool pre = ws_size >= (size_t)EMBBF_OFF + EMBBF_BYTES;

  prep_kernel<<<pre ? 2532 : 32, 256, 0, stream>>>(
      W_trans, W_ht, W_rel, emb_table, ws);

  if (pre)
    fused_bt<true><<<BB * TT, 1024, 0, stream>>>(
        triples, emb_table, emb_bf, b_trans, b_ht, b_rel, sent_triples, ws, out);
  else
    fused_bt<false><<<BB * TT, 1024, 0, stream>>>(
        triples, emb_table, emb_bf, b_trans, b_ht, b_rel, sent_triples, ws, out);
}